// Round 4
// baseline (104.411 us; speedup 1.0000x reference)
//
#include <hip/hip_runtime.h>
#include <hip/hip_bf16.h>
#include <math.h>

#define F 8
#define C 4096
#define NPAIR 36            // F*(F+1)/2 pairs with i<=j
#define EPSF 1e-8f
#define NBLK 1024           // kernel-1 grid: 4 rows p per block (1 per wave)
#define QTILE 1024          // q-tile size; 8 factors * 1024 * 4B = 32 KB LDS

// Accumulator layout in ws (floats): 8 banks x 80 floats.
// Within a bank: G[36] | D[36] | T[8]. Banks spread atomic contention
// (blockIdx & 7); finish_kernel sums the 8 banks.
#define ACC_G 0
#define ACC_D 36
#define ACC_T 72
#define ACC_N 80
#define NBANK 8

__device__ __forceinline__ float wave_reduce(float v) {
    #pragma unroll
    for (int off = 32; off > 0; off >>= 1) v += __shfl_down(v, off, 64);
    return v;
}

// raw v_sqrt_f32 (epilogue only; main loop uses |d| since sqrt(d^2+1e-8)=|d|
// to within 1e-4 absolute, and only at d==0).
__device__ __forceinline__ float fast_sqrt(float v) {
    return __builtin_amdgcn_sqrtf(v);
}

__global__ __launch_bounds__(256) void zero_kernel(float* __restrict__ acc) {
    const int tid = threadIdx.x;
    if (tid < ACC_N * NBANK) acc[tid] = 0.0f;
}

__global__ __launch_bounds__(256) void pair_kernel(const float* __restrict__ x,
                                                   float* __restrict__ acc) {
    __shared__ __align__(16) float xs[F * QTILE];   // 32 KB; reused for reduce
    const int tid  = threadIdx.x;
    const int lane = tid & 63;
    const int wave = tid >> 6;
    const int p    = blockIdx.x * 4 + wave;         // one row per wave

    float xp[F];
    #pragma unroll
    for (int f = 0; f < F; ++f) xp[f] = x[f * C + p];

    float g[NPAIR];
    #pragma unroll
    for (int k = 0; k < NPAIR; ++k) g[k] = 0.0f;
    float rs[F];
    #pragma unroll
    for (int f = 0; f < F; ++f) rs[f] = 0.0f;

    const float4* xg = (const float4*)x;

    for (int tile = 0; tile < C / QTILE; ++tile) {
        const int qb4 = (tile * QTILE) >> 2;        // float4 base of this tile
        __syncthreads();
        // stage 8 factors x 1024 floats = 2048 float4, 8 per thread, coalesced
        for (int i = tid; i < F * (QTILE / 4); i += 256) {
            const int f  = i >> 8;                  // / (QTILE/4)
            const int qq = i & (QTILE / 4 - 1);
            ((float4*)xs)[i] = xg[f * (C / 4) + qb4 + qq];
        }
        __syncthreads();

        for (int qt = 0; qt < QTILE / 4; qt += 64) {
            const int qi = qt + lane;               // float4 index within tile
            float4 v[F];
            #pragma unroll
            for (int f = 0; f < F; ++f) v[f] = ((const float4*)xs)[f * (QTILE / 4) + qi];

            // Raw differences; every consumer folds |.| via VOP3 abs source
            // modifiers, and every g update is a single v_fma_f32.
            float d0[F], d1[F], d2[F], d3[F];
            #pragma unroll
            for (int f = 0; f < F; ++f) {
                d0[f] = xp[f] - v[f].x;
                d1[f] = xp[f] - v[f].y;
                d2[f] = xp[f] - v[f].z;
                d3[f] = xp[f] - v[f].w;
                rs[f] += (__builtin_fabsf(d0[f]) + __builtin_fabsf(d1[f])) +
                         (__builtin_fabsf(d2[f]) + __builtin_fabsf(d3[f]));
            }
            int k = 0;
            #pragma unroll
            for (int i = 0; i < F; ++i)
                #pragma unroll
                for (int j = i; j < F; ++j) {
                    g[k] = __builtin_fmaf(__builtin_fabsf(d0[i]), __builtin_fabsf(d0[j]), g[k]);
                    g[k] = __builtin_fmaf(__builtin_fabsf(d1[i]), __builtin_fabsf(d1[j]), g[k]);
                    g[k] = __builtin_fmaf(__builtin_fabsf(d2[i]), __builtin_fabsf(d2[j]), g[k]);
                    g[k] = __builtin_fmaf(__builtin_fabsf(d3[i]), __builtin_fabsf(d3[j]), g[k]);
                    ++k;
                }
        }
    }

    // reduce within each wave (each wave owns one p)
    #pragma unroll
    for (int f = 0; f < F; ++f) rs[f] = wave_reduce(rs[f]);
    #pragma unroll
    for (int k = 0; k < NPAIR; ++k) g[k] = wave_reduce(g[k]);

    __syncthreads();                 // done reading xs; reuse for cross-wave reduce
    float* red = xs;                 // [4][ACC_N]
    if (lane == 0) {
        #pragma unroll
        for (int k = 0; k < NPAIR; ++k) red[wave * ACC_N + ACC_G + k] = g[k];
        // D_ij contribution of this row p: s_i[p] * s_j[p]
        int k = 0;
        #pragma unroll
        for (int i = 0; i < F; ++i)
            #pragma unroll
            for (int j = i; j < F; ++j) { red[wave * ACC_N + ACC_D + k] = rs[i] * rs[j]; ++k; }
        #pragma unroll
        for (int f = 0; f < F; ++f) red[wave * ACC_N + ACC_T + f] = rs[f];
    }
    __syncthreads();
    if (tid < ACC_N) {
        float s = red[tid] + red[ACC_N + tid] + red[2 * ACC_N + tid] + red[3 * ACC_N + tid];
        atomicAdd(acc + (blockIdx.x & (NBANK - 1)) * ACC_N + tid, s);
    }
}

__global__ __launch_bounds__(128) void finish_kernel(const float* __restrict__ acc,
                                                     float* __restrict__ out) {
    __shared__ float A[ACC_N];
    const int tid = threadIdx.x;
    if (tid < ACC_N) {
        float s = 0.0f;
        #pragma unroll
        for (int b = 0; b < NBANK; ++b) s += acc[b * ACC_N + tid];
        A[tid] = s;
    }
    __syncthreads();
    if (tid == 0) {
        const float invC  = 1.0f / (float)C;        // 2^-12, exact
        const float invC2 = invC * invC;            // 2^-24, exact
        float dcov[NPAIR], diag[F];
        int k = 0;
        for (int i = 0; i < F; ++i)
            for (int j = i; j < F; ++j) {
                // S_ij = G/C^2 - 2 D/C^3 + T_i T_j / C^4
                float S = A[ACC_G + k] * invC2 - 2.0f * A[ACC_D + k] * invC2 * invC +
                          (A[ACC_T + i] * invC2) * (A[ACC_T + j] * invC2);
                float dc = fast_sqrt(fmaxf(S, 0.0f) + EPSF);
                dcov[k] = dc;
                if (i == j) diag[i] = dc;
                ++k;
            }
        float cor = 0.0f;
        k = 0;
        for (int i = 0; i < F; ++i)
            for (int j = i; j < F; ++j) {
                if (j > i) cor += dcov[k] * __builtin_amdgcn_rcpf(
                                      fast_sqrt(diag[i] * diag[j] + EPSF));
                ++k;
            }
        out[0] = cor;
    }
}

extern "C" void kernel_launch(void* const* d_in, const int* in_sizes, int n_in,
                              void* d_out, int out_size, void* d_ws, size_t ws_size,
                              hipStream_t stream) {
    const float* x = (const float*)d_in[0];
    float* acc = (float*)d_ws;                   // 8 banks * 80 floats
    float* out = (float*)d_out;

    hipLaunchKernelGGL(zero_kernel,   dim3(1),    dim3(256), 0, stream, acc);
    hipLaunchKernelGGL(pair_kernel,   dim3(NBLK), dim3(256), 0, stream, x, acc);
    hipLaunchKernelGGL(finish_kernel, dim3(1),    dim3(128), 0, stream, acc, out);
}